// Round 12
// baseline (171.251 us; speedup 1.0000x reference)
//
#include <hip/hip_runtime.h>

#define MARGIN 0.3f
#define BIGF 1e30f
#define MAXC 64

constexpr int D = 256;

typedef __attribute__((ext_vector_type(8))) _Float16 f16x8;
typedef __attribute__((ext_vector_type(4))) _Float16 f16x4;
typedef __attribute__((ext_vector_type(4))) float f32x4;

__device__ __forceinline__ void gll16(const void* g, void* l) {
  __builtin_amdgcn_global_load_lds(
      (const __attribute__((address_space(1))) unsigned int*)g,
      (__attribute__((address_space(3))) unsigned int*)l, 16, 0, 0);
}

#define SCB() __builtin_amdgcn_sched_barrier(0)
#define BAR() __builtin_amdgcn_s_barrier()
#define WAITV(N) asm volatile("s_waitcnt vmcnt(" #N ")" ::: "memory")

// ---- K0: fused f16 convert + row-norm + min-init + bucket fill ----
__global__ __launch_bounds__(256)
void k0_prep(const float* __restrict__ E, const int* __restrict__ labels,
             _Float16* __restrict__ H, float* __restrict__ sq,
             unsigned* __restrict__ minAll, unsigned* __restrict__ minAb,
             int* __restrict__ cnt, int* __restrict__ members, int B) {
  int wave = threadIdx.x >> 6, lane = threadIdx.x & 63;
  int row = blockIdx.x * 4 + wave;
  if (row >= B) return;
  float4 v = *(const float4*)&E[(size_t)row * D + lane * 4];
  f16x4 h;
  h.x = (_Float16)v.x; h.y = (_Float16)v.y;
  h.z = (_Float16)v.z; h.w = (_Float16)v.w;
  *(f16x4*)&H[(size_t)row * D + lane * 4] = h;
  float s = v.x * v.x + v.y * v.y + v.z * v.z + v.w * v.w;
#pragma unroll
  for (int off = 32; off; off >>= 1) s += __shfl_xor(s, off);
  if (lane == 0) {
    sq[row] = s;
    minAll[row] = __float_as_uint(BIGF);
    minAb[row] = __float_as_uint(BIGF);
    int lab = labels[row];
    int p = atomicAdd(&cnt[lab], 1);
    if (p < MAXC) members[lab * MAXC + p] = row;
  }
}

// ---- K1: hardest positive per row via bucket list (exact fp32 path) ----
__global__ __launch_bounds__(256)
void k1_dap(const float* __restrict__ E, const int* __restrict__ labels,
            const float* __restrict__ sq, const int* __restrict__ cnt,
            const int* __restrict__ members, float* __restrict__ d_ap,
            int* __restrict__ haspos, int B) {
  int wave = threadIdx.x >> 6, lane = threadIdx.x & 63;
  int i = blockIdx.x * 4 + wave;
  if (i >= B) return;
  float4 a = *(const float4*)&E[(size_t)i * D + lane * 4];
  int li = labels[i];
  int n = min(cnt[li], MAXC);
  float sqi = sq[i];
  float m = -BIGF;
  const int* mem = &members[li * MAXC];
  int p = 0;
  for (; p + 3 < n; p += 4) {
    int j0 = mem[p], j1 = mem[p + 1], j2 = mem[p + 2], j3 = mem[p + 3];
    float4 b0 = *(const float4*)&E[(size_t)j0 * D + lane * 4];
    float4 b1 = *(const float4*)&E[(size_t)j1 * D + lane * 4];
    float4 b2 = *(const float4*)&E[(size_t)j2 * D + lane * 4];
    float4 b3 = *(const float4*)&E[(size_t)j3 * D + lane * 4];
    float s0 = a.x * b0.x + a.y * b0.y + a.z * b0.z + a.w * b0.w;
    float s1 = a.x * b1.x + a.y * b1.y + a.z * b1.z + a.w * b1.w;
    float s2 = a.x * b2.x + a.y * b2.y + a.z * b2.z + a.w * b2.w;
    float s3 = a.x * b3.x + a.y * b3.y + a.z * b3.z + a.w * b3.w;
#pragma unroll
    for (int off = 32; off; off >>= 1) {
      s0 += __shfl_xor(s0, off);
      s1 += __shfl_xor(s1, off);
      s2 += __shfl_xor(s2, off);
      s3 += __shfl_xor(s3, off);
    }
    float d0 = fmaxf(sqi + sq[j0] - 2.f * s0, 0.f);
    float d1 = fmaxf(sqi + sq[j1] - 2.f * s1, 0.f);
    float d2 = fmaxf(sqi + sq[j2] - 2.f * s2, 0.f);
    float d3 = fmaxf(sqi + sq[j3] - 2.f * s3, 0.f);
    if (j0 != i) m = fmaxf(m, d0);
    if (j1 != i) m = fmaxf(m, d1);
    if (j2 != i) m = fmaxf(m, d2);
    if (j3 != i) m = fmaxf(m, d3);
  }
  for (; p < n; ++p) {
    int j = mem[p];
    if (j == i) continue;
    float4 b = *(const float4*)&E[(size_t)j * D + lane * 4];
    float s = a.x * b.x + a.y * b.y + a.z * b.z + a.w * b.w;
#pragma unroll
    for (int off = 32; off; off >>= 1) s += __shfl_xor(s, off);
    m = fmaxf(m, fmaxf(sqi + sq[j] - 2.f * s, 0.f));
  }
  if (lane == 0) {
    d_ap[i] = (n > 1) ? m : -BIGF;
    haspos[i] = (n > 1) ? 1 : 0;
  }
}

// ---- K2 template: MODE bits 1=STAGE+vmcnt, 2=ds_read+MFMA, 4=epilogue.
// MODE=7 is the real R11 kernel (bit-identical). Probes write dummies only.
template<int MODE>
__global__ __launch_bounds__(512)
void k2t(const _Float16* __restrict__ H, const float* __restrict__ sq,
         const float* __restrict__ d_ap, const int* __restrict__ labels,
         unsigned* __restrict__ minAll, unsigned* __restrict__ minAb,
         float* __restrict__ dumf, int T) {
  constexpr bool STG = (MODE & 1) != 0;
  constexpr bool CMP = (MODE & 2) != 0;
  constexpr bool EPI = (MODE & 4) != 0;

  __shared__ __align__(16) unsigned char smem[65536];
  __shared__ float sqI[256], sqJ[256], dapI[256], dapJ[256];
  __shared__ int labI[256], labJ[256];
  __shared__ unsigned smAJ[256], smBJ[256];

  const int tid = threadIdx.x;
  const int lane = tid & 63;
  const int wave = tid >> 6;
  const int wr = wave >> 2, wc = wave & 3;
  const int lo4 = lane & 15, hi4 = lane >> 4;

  const int nwg = gridDim.x;
  const int bid = blockIdx.x;
  const int swz = ((nwg & 7) == 0) ? (bid & 7) * (nwg >> 3) + (bid >> 3) : bid;
  int ti = (int)((sqrtf(8.f * (float)swz + 1.f) - 1.f) * 0.5f);
  while ((ti + 1) * (ti + 2) / 2 <= swz) ++ti;
  while (ti * (ti + 1) / 2 > swz) --ti;
  const int tj = swz - ti * (ti + 1) / 2;
  const int iBase = ti * 256, jBase = tj * 256;
  const bool offdiag = (ti != tj);

  const int f0 = tid, f1 = 512 + tid;
  const int r0 = f0 >> 2, r1 = f1 >> 2;
  const int c0 = (f0 & 3) ^ ((f0 >> 3) & 3);
  const int c1 = (f1 & 3) ^ ((f1 >> 3) & 3);
  const _Float16* gA0 = H + (size_t)(iBase + r0) * D + c0 * 8;
  const _Float16* gA1 = H + (size_t)(iBase + r1) * D + c1 * 8;
  const _Float16* gB0 = H + (size_t)(jBase + r0) * D + c0 * 8;
  const _Float16* gB1 = H + (size_t)(jBase + r1) * D + c1 * 8;

  auto STAGE = [&](int buf, int kt) {
    unsigned char* base = smem + buf * 32768;
    gll16(gA0 + kt * 32, base + f0 * 16);
    gll16(gA1 + kt * 32, base + f1 * 16);
    gll16(gB0 + kt * 32, base + 16384 + f0 * 16);
    gll16(gB1 + kt * 32, base + 16384 + f1 * 16);
  };

  // opaque-zero accumulator init (rule #17: prevents DCE/const-fold in probes)
  float z0 = 0.f;
  asm volatile("" : "+v"(z0));
  f32x4 acc[8][4];
#pragma unroll
  for (int m = 0; m < 8; ++m)
#pragma unroll
    for (int n = 0; n < 4; ++n) acc[m][n] = (f32x4){z0, z0, z0, z0};

  const int pc = hi4 ^ ((lo4 >> 1) & 3);

  auto COMPUTE = [&](int buf) {
    const _Float16* Ab = (const _Float16*)(smem + buf * 32768);
    const _Float16* Bb = Ab + 8192;
    f16x8 aF[8], bF[4];
#pragma unroll
    for (int m = 0; m < 8; ++m)
      aF[m] = *(const f16x8*)(Ab + (wr * 128 + m * 16 + lo4) * 32 + pc * 8);
#pragma unroll
    for (int n = 0; n < 4; ++n)
      bF[n] = *(const f16x8*)(Bb + (wc * 64 + n * 16 + lo4) * 32 + pc * 8);
    __builtin_amdgcn_s_setprio(1);
#pragma unroll
    for (int m = 0; m < 8; ++m)
#pragma unroll
      for (int n = 0; n < 4; ++n)
        acc[m][n] = __builtin_amdgcn_mfma_f32_16x16x32_f16(aF[m], bF[n], acc[m][n], 0, 0, 0);
    __builtin_amdgcn_s_setprio(0);
  };

  if constexpr (STG) { STAGE(0, 0); STAGE(1, 1); }
  if (tid < 256) {
    int gi = iBase + tid, gj = jBase + tid;
    sqI[tid] = sq[gi]; labI[tid] = labels[gi]; dapI[tid] = d_ap[gi];
    sqJ[tid] = sq[gj]; labJ[tid] = labels[gj]; dapJ[tid] = d_ap[gj];
    smAJ[tid] = smBJ[tid] = __float_as_uint(BIGF);
  }
  __syncthreads();

  auto PH = [&](int b, int kt) {
    if constexpr (CMP) COMPUTE(b);
    SCB(); BAR(); SCB();
    if constexpr (STG) { STAGE(b, kt); WAITV(4); }
    SCB(); BAR(); SCB();
  };
  PH(0, 2); PH(1, 3); PH(0, 4); PH(1, 5); PH(0, 6); PH(1, 7);
  if constexpr (CMP) COMPUTE(0);
  SCB(); BAR(); SCB();
  if constexpr (STG) WAITV(0);
  SCB(); BAR(); SCB();
  if constexpr (CMP) COMPUTE(1);

  if constexpr (!EPI) {
    // sink: keep acc (and thus MFMA/ds_read) live without the epilogue
    float s = 0.f;
#pragma unroll
    for (int m = 0; m < 8; ++m)
#pragma unroll
      for (int n = 0; n < 4; ++n)
        s += acc[m][n][0] + acc[m][n][1] + acc[m][n][2] + acc[m][n][3];
    if (lane == 0) dumf[(size_t)bid * 8 + wave] = s;
    return;
  } else {
    __syncthreads();  // stage reads done -> smem reusable as scratch
    unsigned* scr = (unsigned*)smem;  // [2][256][20]
#pragma unroll
    for (int s = 0; s < 20; ++s) scr[s * 512 + tid] = 0xFFFFFFFFu;
    __syncthreads();

    float sjv[4], djv[4];
    int ljv[4];
#pragma unroll
    for (int n = 0; n < 4; ++n) {
      int lj = wc * 64 + n * 16 + lo4;
      sjv[n] = sqJ[lj]; djv[n] = dapJ[lj]; ljv[n] = labJ[lj];
    }
    float cA[4], cB[4];
#pragma unroll
    for (int n = 0; n < 4; ++n) { cA[n] = BIGF; cB[n] = BIGF; }

#pragma unroll
    for (int m = 0; m < 8; ++m) {
#pragma unroll
      for (int reg = 0; reg < 4; ++reg) {
        const int li = wr * 128 + m * 16 + hi4 * 4 + reg;
        const float si = sqI[li], da = dapI[li];
        const int lbi = labI[li];
        float rA = BIGF, rB = BIGF;
#pragma unroll
        for (int n = 0; n < 4; ++n) {
          float dd = fmaxf(fmaf(-2.f, acc[m][n][reg], si + sjv[n]), 0.f);
          float ddm = (ljv[n] != lbi) ? dd : BIGF;
          rA = fminf(rA, ddm);
          rB = fminf(rB, (ddm > da) ? ddm : BIGF);
          if (offdiag) {
            cA[n] = fminf(cA[n], ddm);
            cB[n] = fminf(cB[n], (ddm > djv[n]) ? ddm : BIGF);
          }
        }
        atomicMin(&scr[li * 20 + lo4], __float_as_uint(rA));
        atomicMin(&scr[5120 + li * 20 + lo4], __float_as_uint(rB));
      }
    }
    if (offdiag) {
#pragma unroll
      for (int n = 0; n < 4; ++n) {
        const int lj = wc * 64 + n * 16 + lo4;
        float a = cA[n], b = cB[n];
        a = fminf(a, __shfl_xor(a, 16)); b = fminf(b, __shfl_xor(b, 16));
        a = fminf(a, __shfl_xor(a, 32)); b = fminf(b, __shfl_xor(b, 32));
        if (hi4 == 0) {
          atomicMin(&smAJ[lj], __float_as_uint(a));
          atomicMin(&smBJ[lj], __float_as_uint(b));
        }
      }
    }
    __syncthreads();
    {
      const int q = tid >> 8, i = tid & 255;
      const uint4* p4 = (const uint4*)&scr[q * 5120 + i * 20];
      uint4 a = p4[0], b = p4[1], c = p4[2], d4 = p4[3];
      unsigned u = min(min(min(a.x, a.y), min(a.z, a.w)),
                       min(min(min(b.x, b.y), min(b.z, b.w)),
                           min(min(min(c.x, c.y), min(c.z, c.w)),
                               min(min(d4.x, d4.y), min(d4.z, d4.w)))));
      unsigned* dst = q ? minAb : minAll;
      atomicMin(&dst[iBase + i], u);
      if (offdiag) {
        unsigned w = q ? smBJ[i] : smAJ[i];
        atomicMin(&dst[jBase + i], w);
      }
    }
  }
}

// ---- K3: deterministic final reduction ----
__global__ __launch_bounds__(1024)
void k3_final(const float* __restrict__ d_ap, const int* __restrict__ haspos,
              const unsigned* __restrict__ minAll, const unsigned* __restrict__ minAb,
              float* __restrict__ out, int B) {
  __shared__ float ssum[1024];
  __shared__ int scnt[1024];
  int t = threadIdx.x;
  float lsum = 0.f;
  int lcnt = 0;
  for (int i = t; i < B; i += 1024) {
    float mA = __uint_as_float(minAll[i]);
    float mB = __uint_as_float(minAb[i]);
    float dap = d_ap[i];
    float dan = (mB < dap + MARGIN) ? mB : mA;
    float loss = fmaxf(dap - dan + MARGIN, 0.f);
    if (haspos[i]) { lsum += loss; lcnt += 1; }
  }
  ssum[t] = lsum;
  scnt[t] = lcnt;
  __syncthreads();
  for (int off = 512; off; off >>= 1) {
    if (t < off) { ssum[t] += ssum[t + off]; scnt[t] += scnt[t + off]; }
    __syncthreads();
  }
  if (t == 0) out[0] = ssum[0] / (float)max(scnt[0], 1);
}

extern "C" void kernel_launch(void* const* d_in, const int* in_sizes, int n_in,
                              void* d_out, int out_size, void* d_ws, size_t ws_size,
                              hipStream_t stream) {
  const float* E = (const float*)d_in[0];
  const int* labels = (const int*)d_in[1];
  int B = in_sizes[1];

  float* ws = (float*)d_ws;
  float* sq = ws;                                   // [B]
  float* dap = ws + B;                              // [B]
  int* haspos = (int*)(ws + 2 * B);                 // [B]
  unsigned* minAll = (unsigned*)(ws + 3 * B);       // [B]
  unsigned* minAb = (unsigned*)(ws + 4 * B);        // [B]
  int* cnt = (int*)(ws + 5 * B);                    // [512]
  int* members = cnt + 512;                         // [512*MAXC]
  _Float16* H = (_Float16*)(members + 512 * MAXC);  // [B*D] f16
  unsigned* dumA = (unsigned*)(H + (size_t)B * D);  // [B] probe dummies
  unsigned* dumB = dumA + B;                        // [B]
  float* dumf = (float*)(dumB + B);                 // [nwg*8]
  float* out = (float*)d_out;

  hipMemsetAsync(cnt, 0, 512 * sizeof(int), stream);
  k0_prep<<<(B + 3) / 4, 256, 0, stream>>>(E, labels, H, sq, minAll, minAb, cnt, members, B);
  k1_dap<<<(B + 3) / 4, 256, 0, stream>>>(E, labels, sq, cnt, members, dap, haspos, B);
  int T = B / 256;
  int nwg = T * (T + 1) / 2;
  k2t<7><<<nwg, 512, 0, stream>>>(H, sq, dap, labels, minAll, minAb, dumf, T);
  k3_final<<<1, 1024, 0, stream>>>(dap, haspos, minAll, minAb, out, B);

  // ---- ablation probes (dummy outputs only; timed but correctness-neutral)
  k2t<3><<<nwg, 512, 0, stream>>>(H, sq, dap, labels, dumA, dumB, dumf, T);  // stage+compute
  k2t<2><<<nwg, 512, 0, stream>>>(H, sq, dap, labels, dumA, dumB, dumf, T);  // compute-only
  k2t<4><<<nwg, 512, 0, stream>>>(H, sq, dap, labels, dumA, dumB, dumf, T);  // epilogue-only
  k2t<1><<<nwg, 512, 0, stream>>>(H, sq, dap, labels, dumA, dumB, dumf, T);  // stage-only
}

// Round 13
// 93.409 us; speedup vs baseline: 1.8333x; 1.8333x over previous
//
#include <hip/hip_runtime.h>

#define MARGIN 0.3f
#define BIGF 1e30f
#define MAXC 64

constexpr int D = 256;

typedef __attribute__((ext_vector_type(8))) _Float16 f16x8;
typedef __attribute__((ext_vector_type(4))) _Float16 f16x4;
typedef __attribute__((ext_vector_type(4))) float f32x4;

__device__ __forceinline__ void gll16(const void* g, void* l) {
  __builtin_amdgcn_global_load_lds(
      (const __attribute__((address_space(1))) unsigned int*)g,
      (__attribute__((address_space(3))) unsigned int*)l, 16, 0, 0);
}

#define SCB() __builtin_amdgcn_sched_barrier(0)
#define BAR() __builtin_amdgcn_s_barrier()
#define WAITV(N) asm volatile("s_waitcnt vmcnt(" #N ")" ::: "memory")

// ---- K0: f16 convert into TILED+PRE-SWIZZLED layout + row-norm + init ----
// H_t[panel=row>>8][kt=col>>5][row&255][chunk(16B) ^ ((row>>1)&3)]
// Each (panel,kt) slab = 256x32 f16 = 16KB contiguous -> k2 STAGE reads it
// with lane-linear addresses (1KB contiguous per wave instruction).
__global__ __launch_bounds__(256)
void k0_prep(const float* __restrict__ E, const int* __restrict__ labels,
             _Float16* __restrict__ H, float* __restrict__ sq,
             unsigned* __restrict__ minAll, unsigned* __restrict__ minAb,
             int* __restrict__ cnt, int* __restrict__ members, int B) {
  int wave = threadIdx.x >> 6, lane = threadIdx.x & 63;
  int row = blockIdx.x * 4 + wave;
  if (row >= B) return;
  float4 v = *(const float4*)&E[(size_t)row * D + lane * 4];
  f16x4 h;
  h.x = (_Float16)v.x; h.y = (_Float16)v.y;
  h.z = (_Float16)v.z; h.w = (_Float16)v.w;
  {
    const int panel = row >> 8, r = row & 255;
    const int kt = lane >> 3;
    const int cc = (lane >> 1) & 3;          // 16B chunk within kt slab
    const int slot = cc ^ ((r >> 1) & 3);    // pre-swizzle at write time
    const size_t off = ((size_t)(panel * 8 + kt) * 256 + r) * 32 + slot * 8 + (lane & 1) * 4;
    *(f16x4*)&H[off] = h;
  }
  float s = v.x * v.x + v.y * v.y + v.z * v.z + v.w * v.w;
#pragma unroll
  for (int off = 32; off; off >>= 1) s += __shfl_xor(s, off);
  if (lane == 0) {
    sq[row] = s;
    minAll[row] = __float_as_uint(BIGF);
    minAb[row] = __float_as_uint(BIGF);
    int lab = labels[row];
    int p = atomicAdd(&cnt[lab], 1);
    if (p < MAXC) members[lab * MAXC + p] = row;
  }
}

// ---- K1: hardest positive per row via bucket list (exact fp32 path) ----
__global__ __launch_bounds__(256)
void k1_dap(const float* __restrict__ E, const int* __restrict__ labels,
            const float* __restrict__ sq, const int* __restrict__ cnt,
            const int* __restrict__ members, float* __restrict__ d_ap,
            int* __restrict__ haspos, int B) {
  int wave = threadIdx.x >> 6, lane = threadIdx.x & 63;
  int i = blockIdx.x * 4 + wave;
  if (i >= B) return;
  float4 a = *(const float4*)&E[(size_t)i * D + lane * 4];
  int li = labels[i];
  int n = min(cnt[li], MAXC);
  float sqi = sq[i];
  float m = -BIGF;
  const int* mem = &members[li * MAXC];
  int p = 0;
  for (; p + 3 < n; p += 4) {
    int j0 = mem[p], j1 = mem[p + 1], j2 = mem[p + 2], j3 = mem[p + 3];
    float4 b0 = *(const float4*)&E[(size_t)j0 * D + lane * 4];
    float4 b1 = *(const float4*)&E[(size_t)j1 * D + lane * 4];
    float4 b2 = *(const float4*)&E[(size_t)j2 * D + lane * 4];
    float4 b3 = *(const float4*)&E[(size_t)j3 * D + lane * 4];
    float s0 = a.x * b0.x + a.y * b0.y + a.z * b0.z + a.w * b0.w;
    float s1 = a.x * b1.x + a.y * b1.y + a.z * b1.z + a.w * b1.w;
    float s2 = a.x * b2.x + a.y * b2.y + a.z * b2.z + a.w * b2.w;
    float s3 = a.x * b3.x + a.y * b3.y + a.z * b3.z + a.w * b3.w;
#pragma unroll
    for (int off = 32; off; off >>= 1) {
      s0 += __shfl_xor(s0, off);
      s1 += __shfl_xor(s1, off);
      s2 += __shfl_xor(s2, off);
      s3 += __shfl_xor(s3, off);
    }
    float d0 = fmaxf(sqi + sq[j0] - 2.f * s0, 0.f);
    float d1 = fmaxf(sqi + sq[j1] - 2.f * s1, 0.f);
    float d2 = fmaxf(sqi + sq[j2] - 2.f * s2, 0.f);
    float d3 = fmaxf(sqi + sq[j3] - 2.f * s3, 0.f);
    if (j0 != i) m = fmaxf(m, d0);
    if (j1 != i) m = fmaxf(m, d1);
    if (j2 != i) m = fmaxf(m, d2);
    if (j3 != i) m = fmaxf(m, d3);
  }
  for (; p < n; ++p) {
    int j = mem[p];
    if (j == i) continue;
    float4 b = *(const float4*)&E[(size_t)j * D + lane * 4];
    float s = a.x * b.x + a.y * b.y + a.z * b.z + a.w * b.w;
#pragma unroll
    for (int off = 32; off; off >>= 1) s += __shfl_xor(s, off);
    m = fmaxf(m, fmaxf(sqi + sq[j] - 2.f * s, 0.f));
  }
  if (lane == 0) {
    d_ap[i] = (n > 1) ? m : -BIGF;
    haspos[i] = (n > 1) ? 1 : 0;
  }
}

// ---- K2: 256x256 f16 symmetric Gram, BK=32, tiled-slab coalesced staging.
// STAGE: one 16KB contiguous slab per (tile,kt); each gll16 wave-inst reads
// 1KB contiguous (8 x 128B lines, minimal TA transactions). Fragment reads
// undo the write-time swizzle via pc = hi4 ^ ((lo4>>1)&3) (2-way, free).
// K-schedule + epilogue bit-identical to R11.
__global__ __launch_bounds__(512)
void k2_f16(const _Float16* __restrict__ H, const float* __restrict__ sq,
            const float* __restrict__ d_ap, const int* __restrict__ labels,
            unsigned* __restrict__ minAll, unsigned* __restrict__ minAb, int T) {
  __shared__ __align__(16) unsigned char smem[65536];
  __shared__ float sqI[256], sqJ[256], dapI[256], dapJ[256];
  __shared__ int labI[256], labJ[256];
  __shared__ unsigned smAJ[256], smBJ[256];

  const int tid = threadIdx.x;
  const int lane = tid & 63;
  const int wave = tid >> 6;
  const int wr = wave >> 2, wc = wave & 3;
  const int lo4 = lane & 15, hi4 = lane >> 4;

  const int nwg = gridDim.x;
  const int bid = blockIdx.x;
  const int swz = ((nwg & 7) == 0) ? (bid & 7) * (nwg >> 3) + (bid >> 3) : bid;
  int ti = (int)((sqrtf(8.f * (float)swz + 1.f) - 1.f) * 0.5f);
  while ((ti + 1) * (ti + 2) / 2 <= swz) ++ti;
  while (ti * (ti + 1) / 2 > swz) --ti;
  const int tj = swz - ti * (ti + 1) / 2;
  const int iBase = ti * 256, jBase = tj * 256;
  const bool offdiag = (ti != tj);

  // slab bases (f16 units): slab(panel,kt) = (panel*8+kt)*8192
  const _Float16* HA = H + (size_t)ti * 8 * 8192;
  const _Float16* HB = H + (size_t)tj * 8 * 8192;
  const int f0 = tid, f1 = 512 + tid;

  auto STAGE = [&](int buf, int kt) {
    unsigned char* base = smem + buf * 32768;
    const _Float16* sa = HA + (size_t)kt * 8192;
    const _Float16* sb = HB + (size_t)kt * 8192;
    gll16(sa + f0 * 8, base + f0 * 16);
    gll16(sa + f1 * 8, base + f1 * 16);
    gll16(sb + f0 * 8, base + 16384 + f0 * 16);
    gll16(sb + f1 * 8, base + 16384 + f1 * 16);
  };

  f32x4 acc[8][4];
#pragma unroll
  for (int m = 0; m < 8; ++m)
#pragma unroll
    for (int n = 0; n < 4; ++n) acc[m][n] = (f32x4){0.f, 0.f, 0.f, 0.f};

  const int pc = hi4 ^ ((lo4 >> 1) & 3);  // undo write-time swizzle

  auto COMPUTE = [&](int buf) {
    const _Float16* Ab = (const _Float16*)(smem + buf * 32768);
    const _Float16* Bb = Ab + 8192;
    f16x8 aF[8], bF[4];
#pragma unroll
    for (int m = 0; m < 8; ++m)
      aF[m] = *(const f16x8*)(Ab + (wr * 128 + m * 16 + lo4) * 32 + pc * 8);
#pragma unroll
    for (int n = 0; n < 4; ++n)
      bF[n] = *(const f16x8*)(Bb + (wc * 64 + n * 16 + lo4) * 32 + pc * 8);
    __builtin_amdgcn_s_setprio(1);
#pragma unroll
    for (int m = 0; m < 8; ++m)
#pragma unroll
      for (int n = 0; n < 4; ++n)
        acc[m][n] = __builtin_amdgcn_mfma_f32_16x16x32_f16(aF[m], bF[n], acc[m][n], 0, 0, 0);
    __builtin_amdgcn_s_setprio(0);
  };

  STAGE(0, 0);
  STAGE(1, 1);
  if (tid < 256) {
    int gi = iBase + tid, gj = jBase + tid;
    sqI[tid] = sq[gi]; labI[tid] = labels[gi]; dapI[tid] = d_ap[gi];
    sqJ[tid] = sq[gj]; labJ[tid] = labels[gj]; dapJ[tid] = d_ap[gj];
    smAJ[tid] = smBJ[tid] = __float_as_uint(BIGF);
  }
  __syncthreads();
  COMPUTE(0); SCB(); BAR(); SCB(); STAGE(0, 2);
  WAITV(4); SCB(); BAR(); SCB(); COMPUTE(1); SCB(); BAR(); SCB(); STAGE(1, 3);
  WAITV(4); SCB(); BAR(); SCB(); COMPUTE(0); SCB(); BAR(); SCB(); STAGE(0, 4);
  WAITV(4); SCB(); BAR(); SCB(); COMPUTE(1); SCB(); BAR(); SCB(); STAGE(1, 5);
  WAITV(4); SCB(); BAR(); SCB(); COMPUTE(0); SCB(); BAR(); SCB(); STAGE(0, 6);
  WAITV(4); SCB(); BAR(); SCB(); COMPUTE(1); SCB(); BAR(); SCB(); STAGE(1, 7);
  WAITV(4); SCB(); BAR(); SCB(); COMPUTE(0); SCB(); BAR(); SCB();
  WAITV(0); SCB(); BAR(); SCB(); COMPUTE(1);
  __syncthreads();  // all LDS stage reads done -> smem reusable as scratch

  // ---- epilogue phase 0: init scratch [2][256][20] uints over stage LDS
  unsigned* scr = (unsigned*)smem;   // 2*256*20*4 = 40960 B
#pragma unroll
  for (int s = 0; s < 20; ++s) scr[s * 512 + tid] = 0xFFFFFFFFu;
  __syncthreads();

  // ---- epilogue phase 1: per-element minima -> LDS uint atomics ----
  float sjv[4], djv[4];
  int ljv[4];
#pragma unroll
  for (int n = 0; n < 4; ++n) {
    int lj = wc * 64 + n * 16 + lo4;
    sjv[n] = sqJ[lj]; djv[n] = dapJ[lj]; ljv[n] = labJ[lj];
  }
  float cA[4], cB[4];
#pragma unroll
  for (int n = 0; n < 4; ++n) { cA[n] = BIGF; cB[n] = BIGF; }

#pragma unroll
  for (int m = 0; m < 8; ++m) {
#pragma unroll
    for (int reg = 0; reg < 4; ++reg) {
      const int li = wr * 128 + m * 16 + hi4 * 4 + reg;
      const float si = sqI[li], da = dapI[li];
      const int lbi = labI[li];
      float rA = BIGF, rB = BIGF;
#pragma unroll
      for (int n = 0; n < 4; ++n) {
        float dd = fmaxf(fmaf(-2.f, acc[m][n][reg], si + sjv[n]), 0.f);
        float ddm = (ljv[n] != lbi) ? dd : BIGF;
        rA = fminf(rA, ddm);
        rB = fminf(rB, (ddm > da) ? ddm : BIGF);
        if (offdiag) {
          cA[n] = fminf(cA[n], ddm);
          cB[n] = fminf(cB[n], (ddm > djv[n]) ? ddm : BIGF);
        }
      }
      atomicMin(&scr[li * 20 + lo4], __float_as_uint(rA));
      atomicMin(&scr[5120 + li * 20 + lo4], __float_as_uint(rB));
    }
  }
  if (offdiag) {
#pragma unroll
    for (int n = 0; n < 4; ++n) {
      const int lj = wc * 64 + n * 16 + lo4;
      float a = cA[n], b = cB[n];
      a = fminf(a, __shfl_xor(a, 16)); b = fminf(b, __shfl_xor(b, 16));
      a = fminf(a, __shfl_xor(a, 32)); b = fminf(b, __shfl_xor(b, 32));
      if (hi4 == 0) {
        atomicMin(&smAJ[lj], __float_as_uint(a));
        atomicMin(&smBJ[lj], __float_as_uint(b));
      }
    }
  }
  __syncthreads();

  // ---- epilogue phase 2: 512 threads, one (quantity,row); uint-min tree
  {
    const int q = tid >> 8, i = tid & 255;
    const uint4* p4 = (const uint4*)&scr[q * 5120 + i * 20];
    uint4 a = p4[0], b = p4[1], c = p4[2], d4 = p4[3];
    unsigned u = min(min(min(a.x, a.y), min(a.z, a.w)),
                     min(min(min(b.x, b.y), min(b.z, b.w)),
                         min(min(min(c.x, c.y), min(c.z, c.w)),
                             min(min(d4.x, d4.y), min(d4.z, d4.w)))));
    unsigned* dst = q ? minAb : minAll;
    atomicMin(&dst[iBase + i], u);
    if (offdiag) {
      unsigned w = q ? smBJ[i] : smAJ[i];
      atomicMin(&dst[jBase + i], w);
    }
  }
}

// ---- K3: deterministic final reduction ----
__global__ __launch_bounds__(1024)
void k3_final(const float* __restrict__ d_ap, const int* __restrict__ haspos,
              const unsigned* __restrict__ minAll, const unsigned* __restrict__ minAb,
              float* __restrict__ out, int B) {
  __shared__ float ssum[1024];
  __shared__ int scnt[1024];
  int t = threadIdx.x;
  float lsum = 0.f;
  int lcnt = 0;
  for (int i = t; i < B; i += 1024) {
    float mA = __uint_as_float(minAll[i]);
    float mB = __uint_as_float(minAb[i]);
    float dap = d_ap[i];
    float dan = (mB < dap + MARGIN) ? mB : mA;
    float loss = fmaxf(dap - dan + MARGIN, 0.f);
    if (haspos[i]) { lsum += loss; lcnt += 1; }
  }
  ssum[t] = lsum;
  scnt[t] = lcnt;
  __syncthreads();
  for (int off = 512; off; off >>= 1) {
    if (t < off) { ssum[t] += ssum[t + off]; scnt[t] += scnt[t + off]; }
    __syncthreads();
  }
  if (t == 0) out[0] = ssum[0] / (float)max(scnt[0], 1);
}

extern "C" void kernel_launch(void* const* d_in, const int* in_sizes, int n_in,
                              void* d_out, int out_size, void* d_ws, size_t ws_size,
                              hipStream_t stream) {
  const float* E = (const float*)d_in[0];
  const int* labels = (const int*)d_in[1];
  int B = in_sizes[1];

  float* ws = (float*)d_ws;
  float* sq = ws;                                   // [B]
  float* dap = ws + B;                              // [B]
  int* haspos = (int*)(ws + 2 * B);                 // [B]
  unsigned* minAll = (unsigned*)(ws + 3 * B);       // [B]
  unsigned* minAb = (unsigned*)(ws + 4 * B);        // [B]
  int* cnt = (int*)(ws + 5 * B);                    // [512]
  int* members = cnt + 512;                         // [512*MAXC]
  _Float16* H = (_Float16*)(members + 512 * MAXC);  // [B*D] f16, tiled layout
  float* out = (float*)d_out;

  hipMemsetAsync(cnt, 0, 512 * sizeof(int), stream);
  k0_prep<<<(B + 3) / 4, 256, 0, stream>>>(E, labels, H, sq, minAll, minAb, cnt, members, B);
  k1_dap<<<(B + 3) / 4, 256, 0, stream>>>(E, labels, sq, cnt, members, dap, haspos, B);
  int T = B / 256;
  int nwg = T * (T + 1) / 2;
  k2_f16<<<nwg, 512, 0, stream>>>(H, sq, dap, labels, minAll, minAb, T);
  k3_final<<<1, 1024, 0, stream>>>(dap, haspos, minAll, minAb, out, B);
}

// Round 14
// 78.961 us; speedup vs baseline: 2.1688x; 1.1830x over previous
//
#include <hip/hip_runtime.h>

#define MARGIN 0.3f
#define BIGF 1e30f
#define MAXC 64

constexpr int D = 256;

typedef __attribute__((ext_vector_type(8))) _Float16 f16x8;
typedef __attribute__((ext_vector_type(4))) _Float16 f16x4;
typedef __attribute__((ext_vector_type(4))) float f32x4;

__device__ __forceinline__ void gll16(const void* g, void* l) {
  __builtin_amdgcn_global_load_lds(
      (const __attribute__((address_space(1))) unsigned int*)g,
      (__attribute__((address_space(3))) unsigned int*)l, 16, 0, 0);
}

#define SCB() __builtin_amdgcn_sched_barrier(0)
#define BAR() __builtin_amdgcn_s_barrier()
#define WAITV(N) asm volatile("s_waitcnt vmcnt(" #N ")" ::: "memory")

// ---- K0: f16 convert into TILED+PRE-SWIZZLED slab layout (as R13) ----
// H_t[panel=row>>8][kt=col>>5][row&255][chunk ^ ((row>>1)&3)]
__global__ __launch_bounds__(256)
void k0_prep(const float* __restrict__ E, const int* __restrict__ labels,
             _Float16* __restrict__ H, float* __restrict__ sq,
             unsigned* __restrict__ minAll, unsigned* __restrict__ minAb,
             int* __restrict__ cnt, int* __restrict__ members, int B) {
  int wave = threadIdx.x >> 6, lane = threadIdx.x & 63;
  int row = blockIdx.x * 4 + wave;
  if (row >= B) return;
  float4 v = *(const float4*)&E[(size_t)row * D + lane * 4];
  f16x4 h;
  h.x = (_Float16)v.x; h.y = (_Float16)v.y;
  h.z = (_Float16)v.z; h.w = (_Float16)v.w;
  {
    const int panel = row >> 8, r = row & 255;
    const int kt = lane >> 3;
    const int cc = (lane >> 1) & 3;
    const int slot = cc ^ ((r >> 1) & 3);
    const size_t off = ((size_t)(panel * 8 + kt) * 256 + r) * 32 + slot * 8 + (lane & 1) * 4;
    *(f16x4*)&H[off] = h;
  }
  float s = v.x * v.x + v.y * v.y + v.z * v.z + v.w * v.w;
#pragma unroll
  for (int off = 32; off; off >>= 1) s += __shfl_xor(s, off);
  if (lane == 0) {
    sq[row] = s;
    minAll[row] = __float_as_uint(BIGF);
    minAb[row] = __float_as_uint(BIGF);
    int lab = labels[row];
    int p = atomicAdd(&cnt[lab], 1);
    if (p < MAXC) members[lab * MAXC + p] = row;
  }
}

// ---- K1: hardest positive per row via bucket list (exact fp32 path) ----
__global__ __launch_bounds__(256)
void k1_dap(const float* __restrict__ E, const int* __restrict__ labels,
            const float* __restrict__ sq, const int* __restrict__ cnt,
            const int* __restrict__ members, float* __restrict__ d_ap,
            int* __restrict__ haspos, int B) {
  int wave = threadIdx.x >> 6, lane = threadIdx.x & 63;
  int i = blockIdx.x * 4 + wave;
  if (i >= B) return;
  float4 a = *(const float4*)&E[(size_t)i * D + lane * 4];
  int li = labels[i];
  int n = min(cnt[li], MAXC);
  float sqi = sq[i];
  float m = -BIGF;
  const int* mem = &members[li * MAXC];
  int p = 0;
  for (; p + 3 < n; p += 4) {
    int j0 = mem[p], j1 = mem[p + 1], j2 = mem[p + 2], j3 = mem[p + 3];
    float4 b0 = *(const float4*)&E[(size_t)j0 * D + lane * 4];
    float4 b1 = *(const float4*)&E[(size_t)j1 * D + lane * 4];
    float4 b2 = *(const float4*)&E[(size_t)j2 * D + lane * 4];
    float4 b3 = *(const float4*)&E[(size_t)j3 * D + lane * 4];
    float s0 = a.x * b0.x + a.y * b0.y + a.z * b0.z + a.w * b0.w;
    float s1 = a.x * b1.x + a.y * b1.y + a.z * b1.z + a.w * b1.w;
    float s2 = a.x * b2.x + a.y * b2.y + a.z * b2.z + a.w * b2.w;
    float s3 = a.x * b3.x + a.y * b3.y + a.z * b3.z + a.w * b3.w;
#pragma unroll
    for (int off = 32; off; off >>= 1) {
      s0 += __shfl_xor(s0, off);
      s1 += __shfl_xor(s1, off);
      s2 += __shfl_xor(s2, off);
      s3 += __shfl_xor(s3, off);
    }
    float d0 = fmaxf(sqi + sq[j0] - 2.f * s0, 0.f);
    float d1 = fmaxf(sqi + sq[j1] - 2.f * s1, 0.f);
    float d2 = fmaxf(sqi + sq[j2] - 2.f * s2, 0.f);
    float d3 = fmaxf(sqi + sq[j3] - 2.f * s3, 0.f);
    if (j0 != i) m = fmaxf(m, d0);
    if (j1 != i) m = fmaxf(m, d1);
    if (j2 != i) m = fmaxf(m, d2);
    if (j3 != i) m = fmaxf(m, d3);
  }
  for (; p < n; ++p) {
    int j = mem[p];
    if (j == i) continue;
    float4 b = *(const float4*)&E[(size_t)j * D + lane * 4];
    float s = a.x * b.x + a.y * b.y + a.z * b.z + a.w * b.w;
#pragma unroll
    for (int off = 32; off; off >>= 1) s += __shfl_xor(s, off);
    m = fmaxf(m, fmaxf(sqi + sq[j] - 2.f * s, 0.f));
  }
  if (lane == 0) {
    d_ap[i] = (n > 1) ? m : -BIGF;
    haspos[i] = (n > 1) ? 1 : 0;
  }
}

// ---- K2: 128x128 f16 symmetric Gram, 4 waves, 4 blocks/CU ----------------
// 2080 jobs / 1024 slots -> fine-grained makespan (~3 x T_128) instead of
// 2 x T_256 (528/512 quantization). Same BK=32 counted-vmcnt schedule,
// slab staging (half-slab per 128-band), kt-ascending MFMA -> bit-identical.
__global__ __launch_bounds__(256, 4)
void k2_f16(const _Float16* __restrict__ H, const float* __restrict__ sq,
            const float* __restrict__ d_ap, const int* __restrict__ labels,
            unsigned* __restrict__ minAll, unsigned* __restrict__ minAb, int T) {
  __shared__ __align__(16) unsigned char smem[32768];  // 2 bufs x (A 8K + B 8K)
  __shared__ float sqI[128], sqJ[128], dapI[128], dapJ[128];
  __shared__ int labI[128], labJ[128];
  __shared__ unsigned smAJ[128], smBJ[128];

  const int tid = threadIdx.x;
  const int lane = tid & 63;
  const int wave = tid >> 6;
  const int wr = wave >> 1, wc = wave & 1;
  const int lo4 = lane & 15, hi4 = lane >> 4;

  const int nwg = gridDim.x;
  const int bid = blockIdx.x;
  const int swz = ((nwg & 7) == 0) ? (bid & 7) * (nwg >> 3) + (bid >> 3) : bid;
  int ti = (int)((sqrtf(8.f * (float)swz + 1.f) - 1.f) * 0.5f);
  while ((ti + 1) * (ti + 2) / 2 <= swz) ++ti;
  while (ti * (ti + 1) / 2 > swz) --ti;
  const int tj = swz - ti * (ti + 1) / 2;
  const int iBase = ti * 128, jBase = tj * 128;
  const bool offdiag = (ti != tj);

  // half-slab bases: band b -> panel b>>1, half (b&1)*4096 f16
  const _Float16* HA = H + (size_t)(ti >> 1) * 8 * 8192 + (size_t)(ti & 1) * 4096;
  const _Float16* HB = H + (size_t)(tj >> 1) * 8 * 8192 + (size_t)(tj & 1) * 4096;
  const int f0 = tid, f1 = 256 + tid;  // 512 slots = 128 rows x 4 chunks

  auto STAGE = [&](int buf, int kt) {
    unsigned char* base = smem + buf * 16384;
    const _Float16* sa = HA + (size_t)kt * 8192;
    const _Float16* sb = HB + (size_t)kt * 8192;
    gll16(sa + f0 * 8, base + f0 * 16);
    gll16(sa + f1 * 8, base + f1 * 16);
    gll16(sb + f0 * 8, base + 8192 + f0 * 16);
    gll16(sb + f1 * 8, base + 8192 + f1 * 16);
  };

  f32x4 acc[4][4];
#pragma unroll
  for (int m = 0; m < 4; ++m)
#pragma unroll
    for (int n = 0; n < 4; ++n) acc[m][n] = (f32x4){0.f, 0.f, 0.f, 0.f};

  const int pc = hi4 ^ ((lo4 >> 1) & 3);  // undo write-time swizzle

  auto COMPUTE = [&](int buf) {
    const _Float16* Ab = (const _Float16*)(smem + buf * 16384);
    const _Float16* Bb = Ab + 4096;
    f16x8 aF[4], bF[4];
#pragma unroll
    for (int m = 0; m < 4; ++m)
      aF[m] = *(const f16x8*)(Ab + (wr * 64 + m * 16 + lo4) * 32 + pc * 8);
#pragma unroll
    for (int n = 0; n < 4; ++n)
      bF[n] = *(const f16x8*)(Bb + (wc * 64 + n * 16 + lo4) * 32 + pc * 8);
    __builtin_amdgcn_s_setprio(1);
#pragma unroll
    for (int m = 0; m < 4; ++m)
#pragma unroll
      for (int n = 0; n < 4; ++n)
        acc[m][n] = __builtin_amdgcn_mfma_f32_16x16x32_f16(aF[m], bF[n], acc[m][n], 0, 0, 0);
    __builtin_amdgcn_s_setprio(0);
  };

  STAGE(0, 0);
  STAGE(1, 1);
  if (tid < 128) {
    int gi = iBase + tid;
    sqI[tid] = sq[gi]; labI[tid] = labels[gi]; dapI[tid] = d_ap[gi];
  } else {
    int t = tid - 128;
    int gj = jBase + t;
    sqJ[t] = sq[gj]; labJ[t] = labels[gj]; dapJ[t] = d_ap[gj];
    smAJ[t] = smBJ[t] = __float_as_uint(BIGF);
  }
  __syncthreads();                      // drains prologue stages (kt 0,1)
  COMPUTE(0); SCB(); BAR(); SCB(); STAGE(0, 2);
  WAITV(4); SCB(); BAR(); SCB(); COMPUTE(1); SCB(); BAR(); SCB(); STAGE(1, 3);
  WAITV(4); SCB(); BAR(); SCB(); COMPUTE(0); SCB(); BAR(); SCB(); STAGE(0, 4);
  WAITV(4); SCB(); BAR(); SCB(); COMPUTE(1); SCB(); BAR(); SCB(); STAGE(1, 5);
  WAITV(4); SCB(); BAR(); SCB(); COMPUTE(0); SCB(); BAR(); SCB(); STAGE(0, 6);
  WAITV(4); SCB(); BAR(); SCB(); COMPUTE(1); SCB(); BAR(); SCB(); STAGE(1, 7);
  WAITV(4); SCB(); BAR(); SCB(); COMPUTE(0); SCB(); BAR(); SCB();
  WAITV(0); SCB(); BAR(); SCB(); COMPUTE(1);
  __syncthreads();  // all LDS stage reads done -> smem reusable as scratch

  // ---- epilogue phase 0: init scratch [2][128][20] uints over stage LDS
  unsigned* scr = (unsigned*)smem;   // 5120 uints = 20480 B
#pragma unroll
  for (int s = 0; s < 20; ++s) scr[s * 256 + tid] = 0xFFFFFFFFu;
  __syncthreads();

  // ---- epilogue phase 1: per-element minima -> LDS uint atomics ----
  float sjv[4], djv[4];
  int ljv[4];
#pragma unroll
  for (int n = 0; n < 4; ++n) {
    int lj = wc * 64 + n * 16 + lo4;
    sjv[n] = sqJ[lj]; djv[n] = dapJ[lj]; ljv[n] = labJ[lj];
  }
  float cA[4], cB[4];
#pragma unroll
  for (int n = 0; n < 4; ++n) { cA[n] = BIGF; cB[n] = BIGF; }

#pragma unroll
  for (int m = 0; m < 4; ++m) {
#pragma unroll
    for (int reg = 0; reg < 4; ++reg) {
      const int li = wr * 64 + m * 16 + hi4 * 4 + reg;
      const float si = sqI[li], da = dapI[li];
      const int lbi = labI[li];
      float rA = BIGF, rB = BIGF;
#pragma unroll
      for (int n = 0; n < 4; ++n) {
        float dd = fmaxf(fmaf(-2.f, acc[m][n][reg], si + sjv[n]), 0.f);
        float ddm = (ljv[n] != lbi) ? dd : BIGF;
        rA = fminf(rA, ddm);
        rB = fminf(rB, (ddm > da) ? ddm : BIGF);
        if (offdiag) {
          cA[n] = fminf(cA[n], ddm);
          cB[n] = fminf(cB[n], (ddm > djv[n]) ? ddm : BIGF);
        }
      }
      atomicMin(&scr[li * 20 + lo4], __float_as_uint(rA));
      atomicMin(&scr[2560 + li * 20 + lo4], __float_as_uint(rB));
    }
  }
  if (offdiag) {
#pragma unroll
    for (int n = 0; n < 4; ++n) {
      const int lj = wc * 64 + n * 16 + lo4;
      float a = cA[n], b = cB[n];
      a = fminf(a, __shfl_xor(a, 16)); b = fminf(b, __shfl_xor(b, 16));
      a = fminf(a, __shfl_xor(a, 32)); b = fminf(b, __shfl_xor(b, 32));
      if (hi4 == 0) {
        atomicMin(&smAJ[lj], __float_as_uint(a));
        atomicMin(&smBJ[lj], __float_as_uint(b));
      }
    }
  }
  __syncthreads();

  // ---- epilogue phase 2: 256 threads, one (quantity,row); uint-min tree
  {
    const int q = tid >> 7, i = tid & 127;
    const uint4* p4 = (const uint4*)&scr[q * 2560 + i * 20];
    uint4 a = p4[0], b = p4[1], c = p4[2], d4 = p4[3];
    unsigned u = min(min(min(a.x, a.y), min(a.z, a.w)),
                     min(min(min(b.x, b.y), min(b.z, b.w)),
                         min(min(min(c.x, c.y), min(c.z, c.w)),
                             min(min(d4.x, d4.y), min(d4.z, d4.w)))));
    unsigned* dst = q ? minAb : minAll;
    atomicMin(&dst[iBase + i], u);
    if (offdiag) {
      unsigned w = q ? smBJ[i] : smAJ[i];
      atomicMin(&dst[jBase + i], w);
    }
  }
}

// ---- K3: deterministic final reduction ----
__global__ __launch_bounds__(1024)
void k3_final(const float* __restrict__ d_ap, const int* __restrict__ haspos,
              const unsigned* __restrict__ minAll, const unsigned* __restrict__ minAb,
              float* __restrict__ out, int B) {
  __shared__ float ssum[1024];
  __shared__ int scnt[1024];
  int t = threadIdx.x;
  float lsum = 0.f;
  int lcnt = 0;
  for (int i = t; i < B; i += 1024) {
    float mA = __uint_as_float(minAll[i]);
    float mB = __uint_as_float(minAb[i]);
    float dap = d_ap[i];
    float dan = (mB < dap + MARGIN) ? mB : mA;
    float loss = fmaxf(dap - dan + MARGIN, 0.f);
    if (haspos[i]) { lsum += loss; lcnt += 1; }
  }
  ssum[t] = lsum;
  scnt[t] = lcnt;
  __syncthreads();
  for (int off = 512; off; off >>= 1) {
    if (t < off) { ssum[t] += ssum[t + off]; scnt[t] += scnt[t + off]; }
    __syncthreads();
  }
  if (t == 0) out[0] = ssum[0] / (float)max(scnt[0], 1);
}

extern "C" void kernel_launch(void* const* d_in, const int* in_sizes, int n_in,
                              void* d_out, int out_size, void* d_ws, size_t ws_size,
                              hipStream_t stream) {
  const float* E = (const float*)d_in[0];
  const int* labels = (const int*)d_in[1];
  int B = in_sizes[1];

  float* ws = (float*)d_ws;
  float* sq = ws;                                   // [B]
  float* dap = ws + B;                              // [B]
  int* haspos = (int*)(ws + 2 * B);                 // [B]
  unsigned* minAll = (unsigned*)(ws + 3 * B);       // [B]
  unsigned* minAb = (unsigned*)(ws + 4 * B);        // [B]
  int* cnt = (int*)(ws + 5 * B);                    // [512]
  int* members = cnt + 512;                         // [512*MAXC]
  _Float16* H = (_Float16*)(members + 512 * MAXC);  // [B*D] f16, tiled layout
  float* out = (float*)d_out;

  hipMemsetAsync(cnt, 0, 512 * sizeof(int), stream);
  k0_prep<<<(B + 3) / 4, 256, 0, stream>>>(E, labels, H, sq, minAll, minAb, cnt, members, B);
  k1_dap<<<(B + 3) / 4, 256, 0, stream>>>(E, labels, sq, cnt, members, dap, haspos, B);
  int T = B / 128;                 // 64
  int nwg = T * (T + 1) / 2;       // 2080
  k2_f16<<<nwg, 256, 0, stream>>>(H, sq, dap, labels, minAll, minAb, T);
  k3_final<<<1, 1024, 0, stream>>>(dap, haspos, minAll, minAb, out, B);
}